// Round 4
// baseline (1566.472 us; speedup 1.0000x reference)
//
#include <hip/hip_runtime.h>
#include <math.h>

// Problem constants
#define BB   64
#define LL   720
#define CC   512
#define FF   361
#define KTOP 20

// ---------------------------------------------------------------------------
// Generic batched tile transpose: in (z, R, Cc) -> out (z, Cc, R)
// grid: (ceil(Cc/32), ceil(R/32), batch), block (32,8)
// ---------------------------------------------------------------------------
__global__ __launch_bounds__(256) void transpose_kernel(
    const float* __restrict__ in, float* __restrict__ out,
    int R, int Cc, long sIn, long sOut) {
  __shared__ float tile[32][33];
  const float* inp = in + (long)blockIdx.z * sIn;
  float* outp = out + (long)blockIdx.z * sOut;
  int r0 = blockIdx.y * 32, c0 = blockIdx.x * 32;
  int tx = threadIdx.x, ty = threadIdx.y;
#pragma unroll
  for (int i = 0; i < 4; ++i) {
    int r = r0 + ty + 8 * i, c = c0 + tx;
    if (r < R && c < Cc) tile[ty + 8 * i][tx] = inp[(long)r * Cc + c];
  }
  __syncthreads();
#pragma unroll
  for (int i = 0; i < 4; ++i) {
    int c = c0 + ty + 8 * i, r = r0 + tx;
    if (c < Cc && r < R) outp[(long)c * R + r] = tile[tx][ty + 8 * i];
  }
}

// ---------------------------------------------------------------------------
// residual[b,l,c] = x[b,l,c] - xfilt[b,c,l]   (transpose-subtract)
// grid: (16, 23, 64), block (32,8)
// ---------------------------------------------------------------------------
__global__ __launch_bounds__(256) void residual_kernel(
    const float* __restrict__ x, const float* __restrict__ xf,
    float* __restrict__ out) {
  __shared__ float tile[32][33];
  int b = blockIdx.z;
  const float* xfp = xf + (long)b * CC * LL;
  int c0 = blockIdx.x * 32, l0 = blockIdx.y * 32;
  int tx = threadIdx.x, ty = threadIdx.y;
#pragma unroll
  for (int i = 0; i < 4; ++i) {
    int c = c0 + ty + 8 * i, l = l0 + tx;
    if (l < LL) tile[ty + 8 * i][tx] = xfp[(long)c * LL + l];
  }
  __syncthreads();
  long xbase = (long)b * LL * CC;
#pragma unroll
  for (int i = 0; i < 4; ++i) {
    int l = l0 + ty + 8 * i, c = c0 + tx;
    if (l < LL) {
      long off = xbase + (long)l * CC + c;
      out[off] = x[off] - tile[tx][ty + 8 * i];
    }
  }
}

// ---------------------------------------------------------------------------
// One-time twiddle table: ctd[j] = cos(j*2pi/720), f64.
// ---------------------------------------------------------------------------
__global__ __launch_bounds__(256) void init_tw_kernel(double* __restrict__ ctd) {
  int j = blockIdx.x * 256 + threadIdx.x;
  const double W0d = 8.7266462599716478846e-3;  // 2*pi/720
  if (j < 720) ctd[j] = cos((double)j * W0d);
}

// ---------------------------------------------------------------------------
// Per-series DFT (361 freqs) + top-20 magnitude filter + reconstruction.
// v3 (unchanged): 4-frequency symmetry rotation chains, barrier-free shfl
// top-k, f32 reconstruction.
// ---------------------------------------------------------------------------
__global__ __launch_bounds__(192) void dft_topk_kernel(
    const float* __restrict__ xt, const double* __restrict__ ctd,
    float* __restrict__ xfilt) {
  __shared__ double seo[2][361][2];   // [series][t][{e,o}]; t=0 holds {x0,x360}; t=360 zero
  __shared__ float  ctf[720];         // f32 twiddles for reconstruction
  __shared__ float  sres[2][361];     // prescaled w*Re/L
  __shared__ float  sims[2][361];     // prescaled w*Im/L
  __shared__ int    ssel[2][KTOP];

  const int tid = threadIdx.x;
  const long ser0 = (long)blockIdx.x * 2;

  for (int p = tid; p < 722; p += 192) {
    int sp = (p >= 361) ? 1 : 0;
    int t = p - 361 * sp;
    const float* xs = xt + (ser0 + sp) * LL;
    double e, o;
    if (t == 0)       { e = (double)xs[0]; o = (double)xs[360]; }
    else if (t < 360) { double xa = (double)xs[t], xb = (double)xs[720 - t];
                        e = xa + xb; o = xa - xb; }
    else              { e = 0.0; o = 0.0; }
    seo[sp][t][0] = e; seo[sp][t][1] = o;
  }
  for (int j = tid; j < 720; j += 192) ctf[j] = (float)ctd[j];
  __syncthreads();

  const int s = (tid >= 96) ? 1 : 0;
  const int f = tid - 96 * s;     // slot in [0,95]; active if <= 90
  const bool act = (f <= 90);

  const double ca = ctd[f];
  const double sa = ctd[f + 540];
  double c = ca, sn = sa;

  double EC0 = 0, EC1 = 0, EC2 = 0, EC3 = 0;
  double ESd = 0, OCd = 0;
  double OS0 = 0, OS1 = 0, OS2 = 0, OS3 = 0;

  for (int u = 0; u < 90; ++u) {
    const int t = 4 * u + 1;
    double e1 = seo[s][t][0],     o1 = seo[s][t][1];
    double e2 = seo[s][t + 1][0], o2 = seo[s][t + 1][1];
    double e3 = seo[s][t + 2][0], o3 = seo[s][t + 2][1];
    double e4 = seo[s][t + 3][0], o4 = seo[s][t + 3][1];
    EC1 = fma(e1, c, EC1);  ESd = fma(e1, sn, ESd);
    OCd = fma(o1, c, OCd);  OS1 = fma(o1, sn, OS1);
    double c2 = fma(c, ca, -(sn * sa)), s2 = fma(sn, ca, c * sa);
    EC2 = fma(e2, c2, EC2); OS2 = fma(o2, s2, OS2);
    double c3 = fma(c2, ca, -(s2 * sa)), s3 = fma(s2, ca, c2 * sa);
    EC3 = fma(e3, c3, EC3); ESd = fma(e3, -s3, ESd);
    OCd = fma(o3, -c3, OCd); OS3 = fma(o3, s3, OS3);
    double c4 = fma(c3, ca, -(s3 * sa)), s4 = fma(s3, ca, c3 * sa);
    EC0 = fma(e4, c4, EC0); OS0 = fma(o4, s4, OS0);
    double c5 = fma(c4, ca, -(s4 * sa)), s5 = fma(s4, ca, c4 * sa);
    c = c5; sn = s5;
  }

  double reF = 0, imF = 0, reG1 = 0, imG1 = 0, reG2 = 0, imG2 = 0, reG3 = 0, imG3 = 0;
  if (act) {
    double x0 = seo[s][0][0], x360 = seo[s][0][1];
    double xe = (f & 1) ? (x0 - x360) : (x0 + x360);
    reF  = xe + ((EC0 + EC1) + (EC2 + EC3));
    imF  = -((OS0 + OS1) + (OS2 + OS3));
    reG3 = xe + ((EC0 - EC1) + (EC2 - EC3));
    imG3 = (OS0 - OS1) + (OS2 - OS3);
    double ecd = EC0 - EC2, osd = OS0 - OS2;
    reG1 = xe + ecd + ESd;
    imG1 = osd - OCd;
    reG2 = xe + ecd - ESd;
    imG2 = -osd - OCd;
  }
  __syncthreads();

  double* mg = &seo[s][0][0];
  if (act) {
    const double invL = 1.0 / 720.0;
    double s0 = (f == 0) ? invL : 2.0 * invL;
    const double s2d = 2.0 * invL;
    int i3 = 360 - f, i1 = 180 - f, i2 = 180 + f;
    mg[f]  = reF * reF + imF * imF;
    sres[s][f]  = (float)(reF * s0);  sims[s][f]  = (float)(imF * s0);
    mg[i3] = reG3 * reG3 + imG3 * imG3;
    sres[s][i3] = (float)(reG3 * s0); sims[s][i3] = (float)(imG3 * s0);
    mg[i1] = reG1 * reG1 + imG1 * imG1;
    sres[s][i1] = (float)(reG1 * s2d); sims[s][i1] = (float)(imG1 * s2d);
    mg[i2] = reG2 * reG2 + imG2 * imG2;
    sres[s][i2] = (float)(reG2 * s2d); sims[s][i2] = (float)(imG2 * s2d);
  }
  __syncthreads();

  const int wv = tid >> 6, ln = tid & 63;
  if (wv != 1) {
    const int sw = wv >> 1;
    const double* mgw = &seo[sw][0][0];
    double val[6];
#pragma unroll
    for (int j = 0; j < 6; ++j) {
      int idx = ln + 64 * j;
      val[j] = (idx < FF) ? mgw[idx] : -2.0;
    }
    for (int it = 0; it < KTOP; ++it) {
      double v = val[0]; int bi = ln;
#pragma unroll
      for (int j = 1; j < 6; ++j) {
        if (val[j] > v) { v = val[j]; bi = ln + 64 * j; }
      }
#pragma unroll
      for (int off = 1; off < 64; off <<= 1) {
        double ov = __shfl_xor(v, off);
        int oi = __shfl_xor(bi, off);
        if (ov > v || (ov == v && oi < bi)) { v = ov; bi = oi; }
      }
      if (ln == 0) ssel[sw][it] = bi;
      if ((bi & 63) == ln) val[bi >> 6] = -2.0;
    }
  }
  __syncthreads();

  for (int p = tid; p < 1440; p += 192) {
    int sp = (p >= 720) ? 1 : 0;
    int t = p - 720 * sp;
    float acc = 0.f;
#pragma unroll
    for (int it = 0; it < KTOP; ++it) {
      int fk = ssel[sp][it];
      int k = (fk * t) % 720;
      int ks = k + 540; if (ks >= 720) ks -= 720;
      acc = fmaf(sres[sp][fk], ctf[k], acc);
      acc = fmaf(-sims[sp][fk], ctf[ks], acc);
    }
    xfilt[(ser0 + sp) * LL + t] = acc;
  }
}

// ---------------------------------------------------------------------------
// fp32 tiled GEMM, 64x64 tile, 4x4/thread (kept for N=64 case, step 5).
// ---------------------------------------------------------------------------
template <int EPI, int BIASM>
__global__ __launch_bounds__(256) void gemm_f32(
    const float* __restrict__ A, const float* __restrict__ W,
    const float* __restrict__ bias, const float* __restrict__ Cin,
    float* __restrict__ Cout, int M, int N, int K,
    long sA, long sW, long sC) {
  __shared__ float As[16][68];
  __shared__ float Ws[16][68];
  A += (long)blockIdx.z * sA;
  W += (long)blockIdx.z * sW;
  const long zoff = (long)blockIdx.z * sC;
  const int m0 = blockIdx.y * 64, n0 = blockIdx.x * 64;
  const int tid = threadIdx.x;
  const int tx = tid & 15, ty = tid >> 4;
  const int arow = tid >> 2, ac = (tid & 3) * 4;
  const int wrow = tid >> 4, wc = (tid & 15) * 4;

  float acc[4][4] = {};
  for (int k0 = 0; k0 < K; k0 += 16) {
    float4 av;
    int gr = m0 + arow;
    if (gr < M) av = *(const float4*)&A[(long)gr * K + k0 + ac];
    else        av = make_float4(0.f, 0.f, 0.f, 0.f);
    float4 wv = *(const float4*)&W[(long)(k0 + wrow) * N + n0 + wc];
    __syncthreads();
    As[ac + 0][arow] = av.x; As[ac + 1][arow] = av.y;
    As[ac + 2][arow] = av.z; As[ac + 3][arow] = av.w;
    *(float4*)&Ws[wrow][wc] = wv;
    __syncthreads();
#pragma unroll
    for (int kk = 0; kk < 16; ++kk) {
      float4 a = *(const float4*)&As[kk][ty * 4];
      float4 b = *(const float4*)&Ws[kk][tx * 4];
      float aa[4] = {a.x, a.y, a.z, a.w};
      float bb[4] = {b.x, b.y, b.z, b.w};
#pragma unroll
      for (int i = 0; i < 4; ++i)
#pragma unroll
        for (int j = 0; j < 4; ++j)
          acc[i][j] = fmaf(aa[i], bb[j], acc[i][j]);
    }
  }

#pragma unroll
  for (int i = 0; i < 4; ++i) {
    int r = m0 + ty * 4 + i;
    if (r >= M) continue;
    float rb = (BIASM == 2) ? bias[r] : 0.f;
#pragma unroll
    for (int j = 0; j < 4; ++j) {
      int cix = n0 + tx * 4 + j;
      float v = acc[i][j];
      if (BIASM == 1) v += bias[cix];
      if (BIASM == 2) v += rb;
      long off = zoff + (long)r * N + cix;
      if (EPI == 0) Cout[off] = v;
      else if (EPI == 1) Cout[off] = fmaxf(v, 0.f);
      else if (EPI == 2) Cout[off] = fmaxf(v + Cin[off], 0.f);
      else Cout[off] = Cin[off] + fmaxf(v, 0.f);
    }
  }
}

// ---------------------------------------------------------------------------
// fp32 GEMM, BM=128 BN=64, BK=16, 256 threads, 8x4/thread.
// Per kk: 3x ds_read_b128 vs 32 FMA -> ~2x the FMA:LDS issue ratio of the
// 64x64/4x4 kernel, keeping >=2 waves/SIMD for the N=128/256 GEMMs.
// DUAL: second (A2,W2,K2) pass accumulating into the same acc -> fuses
//   C = epi(A@W + A2@W2 + bias)   (steps 6+7: kills the A1 round-trip).
// ---------------------------------------------------------------------------
template <int EPI, int BIASM, bool DUAL>
__global__ __launch_bounds__(256) void gemm_128x64(
    const float* __restrict__ A, const float* __restrict__ W,
    const float* __restrict__ A2, const float* __restrict__ W2,
    const float* __restrict__ bias, const float* __restrict__ Cin,
    float* __restrict__ Cout, int M, int N, int K, int K2,
    long sA, long sC) {
  __shared__ float As[16][132];
  __shared__ float Ws[16][68];
  A += (long)blockIdx.z * sA;
  const long zoff = (long)blockIdx.z * sC;
  const int m0 = blockIdx.y * 128, n0 = blockIdx.x * 64;
  const int tid = threadIdx.x;
  const int tx = tid & 15, ty = tid >> 4;          // 16 x 16 thread grid
  const int arow = tid >> 1, ak = (tid & 1) * 8;   // A: 128 rows x 16 k
  const int wrow = tid >> 4, wc = (tid & 15) * 4;  // W: 16 k x 64 n

  float acc[8][4] = {};
  const float* Ap = A;
  const float* Wp = W;
  int Kc = K;
#pragma unroll 1
  for (int pass = 0; pass < (DUAL ? 2 : 1); ++pass) {
    if (DUAL && pass == 1) { Ap = A2; Wp = W2; Kc = K2; }
    for (int k0 = 0; k0 < Kc; k0 += 16) {
      float4 av0, av1;
      int gr = m0 + arow;
      if (gr < M) {
        av0 = *(const float4*)&Ap[(long)gr * Kc + k0 + ak];
        av1 = *(const float4*)&Ap[(long)gr * Kc + k0 + ak + 4];
      } else {
        av0 = av1 = make_float4(0.f, 0.f, 0.f, 0.f);
      }
      float4 wv = *(const float4*)&Wp[(long)(k0 + wrow) * N + n0 + wc];
      __syncthreads();
      As[ak + 0][arow] = av0.x; As[ak + 1][arow] = av0.y;
      As[ak + 2][arow] = av0.z; As[ak + 3][arow] = av0.w;
      As[ak + 4][arow] = av1.x; As[ak + 5][arow] = av1.y;
      As[ak + 6][arow] = av1.z; As[ak + 7][arow] = av1.w;
      *(float4*)&Ws[wrow][wc] = wv;
      __syncthreads();
#pragma unroll
      for (int kk = 0; kk < 16; ++kk) {
        float4 a0 = *(const float4*)&As[kk][ty * 8];
        float4 a1 = *(const float4*)&As[kk][ty * 8 + 4];
        float4 b  = *(const float4*)&Ws[kk][tx * 4];
        float aa[8] = {a0.x, a0.y, a0.z, a0.w, a1.x, a1.y, a1.z, a1.w};
        float bb[4] = {b.x, b.y, b.z, b.w};
#pragma unroll
        for (int i = 0; i < 8; ++i)
#pragma unroll
          for (int j = 0; j < 4; ++j)
            acc[i][j] = fmaf(aa[i], bb[j], acc[i][j]);
      }
    }
  }

  float4 bc = make_float4(0.f, 0.f, 0.f, 0.f);
  if (BIASM == 1) bc = *(const float4*)&bias[n0 + tx * 4];
#pragma unroll
  for (int i = 0; i < 8; ++i) {
    int r = m0 + ty * 8 + i;
    if (r >= M) continue;
    float rb = (BIASM == 2) ? bias[r] : 0.f;
    long off = zoff + (long)r * N + n0 + tx * 4;
    float4 v = make_float4(acc[i][0], acc[i][1], acc[i][2], acc[i][3]);
    if (BIASM == 1) { v.x += bc.x; v.y += bc.y; v.z += bc.z; v.w += bc.w; }
    if (BIASM == 2) { v.x += rb;   v.y += rb;   v.z += rb;   v.w += rb;   }
    if (EPI == 0) {
      *(float4*)&Cout[off] = v;
    } else if (EPI == 1) {
      v.x = fmaxf(v.x, 0.f); v.y = fmaxf(v.y, 0.f);
      v.z = fmaxf(v.z, 0.f); v.w = fmaxf(v.w, 0.f);
      *(float4*)&Cout[off] = v;
    } else if (EPI == 2) {
      float4 ci = *(const float4*)&Cin[off];
      v.x = fmaxf(v.x + ci.x, 0.f); v.y = fmaxf(v.y + ci.y, 0.f);
      v.z = fmaxf(v.z + ci.z, 0.f); v.w = fmaxf(v.w + ci.w, 0.f);
      *(float4*)&Cout[off] = v;
    } else {
      float4 ci = *(const float4*)&Cin[off];
      v.x = ci.x + fmaxf(v.x, 0.f); v.y = ci.y + fmaxf(v.y, 0.f);
      v.z = ci.z + fmaxf(v.z, 0.f); v.w = ci.w + fmaxf(v.w, 0.f);
      *(float4*)&Cout[off] = v;
    }
  }
}

// ---------------------------------------------------------------------------
// fp32 GEMM, BM=BN=128, BK=16, 256 threads, 8x8/thread.
// Per kk: 4x ds_read_b128 vs 64 FMA. B-fragment (8 floats = 32B stride)
// would 4-way-conflict; Ws is split into two half arrays (16B stride,
// 2-way = free). For channel-mix (M=16384 K=512) and projection
// (M=720 N=512 K=256 x64).
// ---------------------------------------------------------------------------
template <int EPI, int BIASM>
__global__ __launch_bounds__(256) void gemm_128x128(
    const float* __restrict__ A, const float* __restrict__ W,
    const float* __restrict__ bias, const float* __restrict__ Cin,
    float* __restrict__ Cout, int M, int N, int K,
    long sA, long sW, long sC) {
  __shared__ float As[16][132];
  __shared__ float WsA[16][68];   // cols where ((n>>2)&1)==0
  __shared__ float WsB[16][68];   // cols where ((n>>2)&1)==1
  A += (long)blockIdx.z * sA;
  W += (long)blockIdx.z * sW;
  const long zoff = (long)blockIdx.z * sC;
  const int m0 = blockIdx.y * 128, n0 = blockIdx.x * 128;
  const int tid = threadIdx.x;
  const int tx = tid & 15, ty = tid >> 4;
  const int arow = tid >> 1, ak = (tid & 1) * 8;
  const int wrow = tid >> 4, wq = (tid & 15);   // cols wq*8 .. wq*8+7

  float acc[8][8] = {};
  for (int k0 = 0; k0 < K; k0 += 16) {
    float4 av0, av1;
    int gr = m0 + arow;
    if (gr < M) {
      av0 = *(const float4*)&A[(long)gr * K + k0 + ak];
      av1 = *(const float4*)&A[(long)gr * K + k0 + ak + 4];
    } else {
      av0 = av1 = make_float4(0.f, 0.f, 0.f, 0.f);
    }
    const float* wp = &W[(long)(k0 + wrow) * N + n0 + wq * 8];
    float4 wv0 = *(const float4*)&wp[0];
    float4 wv1 = *(const float4*)&wp[4];
    __syncthreads();
    As[ak + 0][arow] = av0.x; As[ak + 1][arow] = av0.y;
    As[ak + 2][arow] = av0.z; As[ak + 3][arow] = av0.w;
    As[ak + 4][arow] = av1.x; As[ak + 5][arow] = av1.y;
    As[ak + 6][arow] = av1.z; As[ak + 7][arow] = av1.w;
    *(float4*)&WsA[wrow][wq * 4] = wv0;
    *(float4*)&WsB[wrow][wq * 4] = wv1;
    __syncthreads();
#pragma unroll
    for (int kk = 0; kk < 16; ++kk) {
      float4 a0 = *(const float4*)&As[kk][ty * 8];
      float4 a1 = *(const float4*)&As[kk][ty * 8 + 4];
      float4 b0 = *(const float4*)&WsA[kk][tx * 4];
      float4 b1 = *(const float4*)&WsB[kk][tx * 4];
      float aa[8] = {a0.x, a0.y, a0.z, a0.w, a1.x, a1.y, a1.z, a1.w};
      float bb[8] = {b0.x, b0.y, b0.z, b0.w, b1.x, b1.y, b1.z, b1.w};
#pragma unroll
      for (int i = 0; i < 8; ++i)
#pragma unroll
        for (int j = 0; j < 8; ++j)
          acc[i][j] = fmaf(aa[i], bb[j], acc[i][j]);
    }
  }

  float4 bc0 = make_float4(0.f, 0.f, 0.f, 0.f), bc1 = bc0;
  if (BIASM == 1) {
    bc0 = *(const float4*)&bias[n0 + tx * 8];
    bc1 = *(const float4*)&bias[n0 + tx * 8 + 4];
  }
#pragma unroll
  for (int i = 0; i < 8; ++i) {
    int r = m0 + ty * 8 + i;
    if (r >= M) continue;
    float rb = (BIASM == 2) ? bias[r] : 0.f;
    long off = zoff + (long)r * N + n0 + tx * 8;
    float4 v0 = make_float4(acc[i][0], acc[i][1], acc[i][2], acc[i][3]);
    float4 v1 = make_float4(acc[i][4], acc[i][5], acc[i][6], acc[i][7]);
    if (BIASM == 1) {
      v0.x += bc0.x; v0.y += bc0.y; v0.z += bc0.z; v0.w += bc0.w;
      v1.x += bc1.x; v1.y += bc1.y; v1.z += bc1.z; v1.w += bc1.w;
    }
    if (BIASM == 2) {
      v0.x += rb; v0.y += rb; v0.z += rb; v0.w += rb;
      v1.x += rb; v1.y += rb; v1.z += rb; v1.w += rb;
    }
    if (EPI == 0) {
      *(float4*)&Cout[off] = v0;
      *(float4*)&Cout[off + 4] = v1;
    } else if (EPI == 1) {
      v0.x = fmaxf(v0.x, 0.f); v0.y = fmaxf(v0.y, 0.f);
      v0.z = fmaxf(v0.z, 0.f); v0.w = fmaxf(v0.w, 0.f);
      v1.x = fmaxf(v1.x, 0.f); v1.y = fmaxf(v1.y, 0.f);
      v1.z = fmaxf(v1.w, 0.f); v1.z = fmaxf(v1.z, 0.f); v1.w = fmaxf(v1.w, 0.f);
      *(float4*)&Cout[off] = v0;
      *(float4*)&Cout[off + 4] = v1;
    } else if (EPI == 2) {
      float4 c0 = *(const float4*)&Cin[off];
      float4 c1 = *(const float4*)&Cin[off + 4];
      v0.x = fmaxf(v0.x + c0.x, 0.f); v0.y = fmaxf(v0.y + c0.y, 0.f);
      v0.z = fmaxf(v0.z + c0.z, 0.f); v0.w = fmaxf(v0.w + c0.w, 0.f);
      v1.x = fmaxf(v1.x + c1.x, 0.f); v1.y = fmaxf(v1.y + c1.y, 0.f);
      v1.z = fmaxf(v1.z + c1.z, 0.f); v1.w = fmaxf(v1.w + c1.w, 0.f);
      *(float4*)&Cout[off] = v0;
      *(float4*)&Cout[off + 4] = v1;
    } else {
      float4 c0 = *(const float4*)&Cin[off];
      float4 c1 = *(const float4*)&Cin[off + 4];
      v0.x = c0.x + fmaxf(v0.x, 0.f); v0.y = c0.y + fmaxf(v0.y, 0.f);
      v0.z = c0.z + fmaxf(v0.z, 0.f); v0.w = c0.w + fmaxf(v0.w, 0.f);
      v1.x = c1.x + fmaxf(v1.x, 0.f); v1.y = c1.y + fmaxf(v1.y, 0.f);
      v1.z = c1.z + fmaxf(v1.z, 0.f); v1.w = c1.w + fmaxf(v1.w, 0.f);
      *(float4*)&Cout[off] = v0;
      *(float4*)&Cout[off + 4] = v1;
    }
  }
}

// ---------------------------------------------------------------------------
extern "C" void kernel_launch(void* const* d_in, const int* in_sizes, int n_in,
                              void* d_out, int out_size, void* d_ws, size_t ws_size,
                              hipStream_t stream) {
  const float* x      = (const float*)d_in[0];
  const float* w_freq = (const float*)d_in[1];
  const float* b_freq = (const float*)d_in[2];
  const float* w_all1 = (const float*)d_in[3];
  const float* b_all1 = (const float*)d_in[4];
  const float* w_all2 = (const float*)d_in[5];
  const float* b_all2 = (const float*)d_in[6];
  const float* w_time = (const float*)d_in[7];
  const float* b_time = (const float*)d_in[8];
  const float* w_chan = (const float*)d_in[9];
  const float* b_chan = (const float*)d_in[10];
  const float* w_proj = (const float*)d_in[11];
  const float* b_proj = (const float*)d_in[12];

  float* out0 = (float*)d_out;                       // residual (64,720,512)
  float* out1 = out0 + (size_t)BB * LL * CC;         // pred     (64,720,512)

  // workspace layout (floats). Peak ~214.6 MB.
  float* ws  = (float*)d_ws;
  float* XT  = ws;                    // (64,512,720)  23,592,960
  float* XF  = XT + 23592960;         // (64,512,720)  23,592,960
  float* H   = XF + 23592960;         // (32768,64)     2,097,152
  float* A1  = H + 2097152;           // (32768,128)    4,194,304
  float* WPT = A1 + 4194304;          // (720,256)        184,320
  float* Z   = XF;                    // reuse XF after h-GEMM: (32768,256)
  float* T   = XF + 8388608;          // (32768,256)
  float* TT  = XT;                    // reuse XT after fused-GEMM: (64,256,512)
  float* CO  = XT + 8388608;          // (64,256,512)
  // twiddle table aliases H: H first written at step 5, CTD consumed at step 3.
  double* CTD = (double*)H;           // 720 doubles

  dim3 tb(32, 8);

  // 0) f64 twiddle table (once per launch; tiny)
  init_tw_kernel<<<3, 256, 0, stream>>>(CTD);
  // 1) x (b,720,512) -> XT (b,512,720)
  transpose_kernel<<<dim3(16, 23, BB), tb, 0, stream>>>(
      x, XT, LL, CC, (long)LL * CC, (long)LL * CC);
  // 2) w_proj (256,720) -> WPT (720,256)
  transpose_kernel<<<dim3(23, 8, 1), tb, 0, stream>>>(
      w_proj, WPT, 256, 720, 0, 0);
  // 3) per-series DFT + top-20 filter -> XF (b,512,720); 2 series/block
  dft_topk_kernel<<<BB * CC / 2, 192, 0, stream>>>(XT, CTD, XF);
  // 4) residual = x - XF^T -> out0
  residual_kernel<<<dim3(16, 23, BB), tb, 0, stream>>>(x, XF, out0);
  // 5) h = relu(XF @ w_freq + b_freq)            (32768,720)x(720,64)
  gemm_f32<1, 1><<<dim3(1, 512, 1), 256, 0, stream>>>(
      XF, w_freq, b_freq, nullptr, H, 32768, 64, 720, 0, 0, 0);
  // 6+7 fused) a1 = relu(XT @ w_all1[64:] + H @ w_all1[:64] + b_all1)
  gemm_128x64<1, 1, true><<<dim3(2, 256, 1), 256, 0, stream>>>(
      XT, w_all1 + 64 * 128, H, w_all1, b_all1, nullptr, A1,
      32768, 128, 720, 64, 0, 0);
  // 8) z = a1 @ w_all2 + b_all2                  (32768,128)x(128,256)
  gemm_128x64<0, 1, false><<<dim3(4, 256, 1), 256, 0, stream>>>(
      A1, w_all2, nullptr, nullptr, b_all2, nullptr, Z,
      32768, 256, 128, 0, 0, 0);
  // 9) t = z + relu(z @ w_time + b_time)         (32768,256)x(256,256)
  gemm_128x64<3, 1, false><<<dim3(4, 256, 1), 256, 0, stream>>>(
      Z, w_time, nullptr, nullptr, b_time, Z, T,
      32768, 256, 256, 0, 0, 0);
  // 10) T (b,512,256) -> TT (b,256,512)
  transpose_kernel<<<dim3(8, 16, BB), tb, 0, stream>>>(
      T, TT, 512, 256, (long)512 * 256, (long)512 * 256);
  // 11) c = TT + relu(TT @ w_chan + b_chan)      (16384,512)x(512,512)
  gemm_128x128<3, 1><<<dim3(4, 128, 1), 256, 0, stream>>>(
      TT, w_chan, b_chan, TT, CO, 16384, 512, 512, 0, 0, 0);
  // 12) pred[b,p,c] = WPT[p,:] @ CO[b,:,c] + b_proj[p]  (720,256)x(256,512) x64
  gemm_128x128<0, 2><<<dim3(4, 6, BB), 256, 0, stream>>>(
      WPT, CO, b_proj, nullptr, out1, 720, 512, 256,
      0, (long)256 * 512, (long)LL * CC);
}